// Round 3
// baseline (1626.284 us; speedup 1.0000x reference)
//
#include <hip/hip_runtime.h>
#include <math.h>

#define N_NODES 50000
#define N_EDGES 800000
#define DIM 128

typedef __attribute__((ext_vector_type(8))) short short8;
typedef __attribute__((ext_vector_type(4))) float floatx4;

// f32 -> bf16 bits, round-to-nearest-even (matches v_cvt / numpy)
__device__ __forceinline__ unsigned short f32_to_bf16(float f) {
    unsigned int u = __float_as_uint(f);
    u += 0x7fffu + ((u >> 16) & 1u);
    return (unsigned short)(u >> 16);
}

// ---------------- CSR build ----------------

__global__ __launch_bounds__(256) void hist_kernel(const int* __restrict__ dst,
                                                   int* __restrict__ deg) {
    int e = blockIdx.x * 256 + threadIdx.x;
    if (e < N_EDGES) atomicAdd(&deg[dst[e]], 1);
}

__global__ __launch_bounds__(1024) void scan_kernel(const int* __restrict__ deg,
                                                    int* __restrict__ rowp) {
    __shared__ int buf[1024];
    __shared__ int carry_s;
    const int n = N_NODES;
    if (threadIdx.x == 0) carry_s = 0;
    __syncthreads();
    for (int base = 0; base < n; base += 1024) {
        int i = base + threadIdx.x;
        int v = (i < n) ? deg[i] : 0;
        buf[threadIdx.x] = v;
        __syncthreads();
        for (int off = 1; off < 1024; off <<= 1) {
            int t = (threadIdx.x >= off) ? buf[threadIdx.x - off] : 0;
            __syncthreads();
            buf[threadIdx.x] += t;
            __syncthreads();
        }
        int incl = buf[threadIdx.x];
        if (i < n) rowp[i] = carry_s + incl - v;   // exclusive scan
        __syncthreads();
        if (threadIdx.x == 0) carry_s += buf[1023];
        __syncthreads();
    }
    if (threadIdx.x == 0) rowp[n] = carry_s;       // == N_EDGES
}

__global__ __launch_bounds__(256) void scatter_kernel(const int* __restrict__ src,
                                                      const int* __restrict__ dst,
                                                      const float* __restrict__ ew,
                                                      int* __restrict__ cursor,
                                                      int* __restrict__ csrc,
                                                      float* __restrict__ cw) {
    int e = blockIdx.x * 256 + threadIdx.x;
    if (e < N_EDGES) {
        int d = dst[e];
        int pos = atomicAdd(&cursor[d], 1);
        csrc[pos] = src[e];
        cw[pos] = ew[e];
    }
}

// ---------------- f32 -> bf16 convert (vectorized) ----------------

__global__ __launch_bounds__(256) void cvt_kernel(const float* __restrict__ in,
                                                  unsigned short* __restrict__ out,
                                                  int n4) {
    int i = blockIdx.x * 256 + threadIdx.x;
    if (i >= n4) return;
    floatx4 v = *(const floatx4*)(in + (size_t)i * 4);
    ushort4 o;
    o.x = f32_to_bf16(v.x);
    o.y = f32_to_bf16(v.y);
    o.z = f32_to_bf16(v.z);
    o.w = f32_to_bf16(v.w);
    *(ushort4*)(out + (size_t)i * 4) = o;
}

// ---------------- fused SpMM + residual mix ----------------
// m = 0.9*(A@h) + 0.1*x0 ; writes m as f32 (exact residual path) and bf16 (MFMA input)

__global__ __launch_bounds__(256) void spmm_fused(const float* __restrict__ h,
                                                  const float* __restrict__ x0,
                                                  const int* __restrict__ rowp,
                                                  const int* __restrict__ csrc,
                                                  const float* __restrict__ cw,
                                                  float* __restrict__ mF,
                                                  unsigned short* __restrict__ mB) {
    int v = blockIdx.x * 2 + (threadIdx.x >> 7);
    int f = threadIdx.x & 127;
    if (v >= N_NODES) return;
    int beg = rowp[v], end = rowp[v + 1];
    float acc = 0.f;
    for (int i = beg; i < end; i++) {
        int s = csrc[i];
        float w = cw[i];
        acc += w * h[(size_t)s * DIM + f];
    }
    size_t off = (size_t)v * DIM + f;
    float m = 0.9f * acc + 0.1f * x0[off];
    mF[off] = m;
    mB[off] = f32_to_bf16(m);
}

// ---------------- MFMA GEMM: out = relu(cm*Mres + cg*(A@W) + bias) ----------------
// A: [N_NODES,128] bf16 row-major. W: [128,128] f32 row-major, cvt->bf16 into LDS^T.
// 4 waves/block, each wave does a 16-row strip x all 128 cols.

__global__ __launch_bounds__(256) void gemm128(const unsigned short* __restrict__ A,
                                               const float* __restrict__ W,
                                               const float* __restrict__ Mres,
                                               const float* __restrict__ bias,
                                               float* __restrict__ outF,
                                               float cm, float cg) {
    __shared__ unsigned short WT[128][136];   // transposed, +8 pad
    for (int idx = threadIdx.x; idx < 128 * 128; idx += 256) {
        int k = idx >> 7, n = idx & 127;
        WT[n][k] = f32_to_bf16(W[idx]);
    }
    __syncthreads();

    int wave = threadIdx.x >> 6;
    int lane = threadIdx.x & 63;
    int r0 = (blockIdx.x * 4 + wave) * 16;
    if (r0 >= N_NODES) return;                 // 16 | 50000, full tiles only

    int mrow = lane & 15;                      // A row within tile; also C col
    int quad = lane >> 4;

    floatx4 acc[8];
#pragma unroll
    for (int t = 0; t < 8; t++) acc[t] = {0.f, 0.f, 0.f, 0.f};

    const unsigned short* arow = A + (size_t)(r0 + mrow) * DIM;
#pragma unroll
    for (int k0 = 0; k0 < 128; k0 += 32) {
        short8 a = *(const short8*)(const void*)(arow + k0 + quad * 8);
#pragma unroll
        for (int t = 0; t < 8; t++) {
            short8 b = *(const short8*)(const void*)(&WT[t * 16 + mrow][k0 + quad * 8]);
            acc[t] = __builtin_amdgcn_mfma_f32_16x16x32_bf16(a, b, acc[t], 0, 0, 0);
        }
    }

    // C/D layout: col = lane&15, row = quad*4 + i  [verified m89/m91]
#pragma unroll
    for (int t = 0; t < 8; t++) {
        int col = t * 16 + mrow;
        float bv = bias ? bias[col] : 0.f;
#pragma unroll
        for (int i = 0; i < 4; i++) {
            int row = r0 + quad * 4 + i;
            size_t off = (size_t)row * DIM + col;
            float v = cg * acc[t][i] + bv;
            if (Mres) v += cm * Mres[off];
            outF[off] = fmaxf(v, 0.f);
        }
    }
}

// ---------------- launch ----------------

extern "C" void kernel_launch(void* const* d_in, const int* in_sizes, int n_in,
                              void* d_out, int out_size, void* d_ws, size_t ws_size,
                              hipStream_t stream) {
    const float* x    = (const float*)d_in[0];
    const float* ew   = (const float*)d_in[1];
    const float* Wlin = (const float*)d_in[2];
    const float* blin = (const float*)d_in[3];
    const float* Wcv  = (const float*)d_in[4];
    const int* eidx = (const int*)d_in[5];
    const int* esrc = eidx;
    const int* edst = eidx + N_EDGES;
    float* out = (float*)d_out;

    char* ws = (char*)d_ws;
    float* x0          = (float*)(ws);                       // 25.6 MB
    float* hbuf        = (float*)(ws + 25600000);            // 25.6 MB
    float* mF          = (float*)(ws + 51200000);            // 25.6 MB
    unsigned short* mB = (unsigned short*)(ws + 76800000);   // 12.8 MB (also holds bf16(x) for first GEMM)
    int* rowp          = (int*)(ws + 89600000);              // (N+1)*4
    int* cursor        = (int*)(ws + 89800064);              // also 'deg'
    int* csrc          = (int*)(ws + 90000128);              // E*4
    float* cwt         = (float*)(ws + 93200128);            // E*4
    // total ~96.4 MB

    // CSR build (every call; no static state)
    (void)hipMemsetAsync(cursor, 0, (N_NODES + 1) * sizeof(int), stream);
    hist_kernel<<<(N_EDGES + 255) / 256, 256, 0, stream>>>(edst, cursor);
    scan_kernel<<<1, 1024, 0, stream>>>(cursor, rowp);
    (void)hipMemcpyAsync(cursor, rowp, N_NODES * sizeof(int), hipMemcpyDeviceToDevice, stream);
    scatter_kernel<<<(N_EDGES + 255) / 256, 256, 0, stream>>>(esrc, edst, ew, cursor, csrc, cwt);

    const int gemm_grid = (N_NODES + 63) / 64;   // 782

    // x -> bf16 (into mB), then x0 = relu(x @ W_lin + b_lin)
    cvt_kernel<<<(N_NODES * DIM / 4 + 255) / 256, 256, 0, stream>>>(x, mB, N_NODES * DIM / 4);
    gemm128<<<gemm_grid, 256, 0, stream>>>(mB, Wlin, nullptr, blin, x0, 0.f, 1.f);

    const float* h = x0;
    for (int l = 0; l < 8; l++) {
        spmm_fused<<<(N_NODES + 1) / 2, 256, 0, stream>>>(h, x0, rowp, csrc, cwt, mF, mB);
        float beta = logf(0.5f / (float)(l + 1) + 1.f);
        float* oF = (l < 7) ? hbuf : out;
        gemm128<<<gemm_grid, 256, 0, stream>>>(mB, Wcv + (size_t)l * DIM * DIM, mF,
                                               nullptr, oF, 1.f - beta, beta);
        h = hbuf;
    }
}

// Round 4
// 1589.632 us; speedup vs baseline: 1.0231x; 1.0231x over previous
//
#include <hip/hip_runtime.h>
#include <math.h>

#define N_NODES 50000
#define N_EDGES 800000
#define DIM 128
#define NCHUNK 4            // 128 features / 32
#define CHUNK 32
#define SPMM_NODES_PER_BLK 8
#define SPMM_BLKS_PER_CHUNK (N_NODES / SPMM_NODES_PER_BLK)   // 6250
#define SCAN_BLOCKS 49      // 49*1024 = 50176 >= 50001

typedef __attribute__((ext_vector_type(8))) short short8;
typedef __attribute__((ext_vector_type(4))) float floatx4;

// f32 -> bf16 bits, round-to-nearest-even (matches v_cvt / numpy)
__device__ __forceinline__ unsigned short f32_to_bf16(float f) {
    unsigned int u = __float_as_uint(f);
    u += 0x7fffu + ((u >> 16) & 1u);
    return (unsigned short)(u >> 16);
}
__device__ __forceinline__ float bf16_to_f32(unsigned short h) {
    return __uint_as_float((unsigned int)h << 16);
}

// ---------------- CSR build ----------------

__global__ __launch_bounds__(256) void hist_kernel(const int* __restrict__ dst,
                                                   int* __restrict__ deg) {
    int e = blockIdx.x * 256 + threadIdx.x;
    if (e < N_EDGES) atomicAdd(&deg[dst[e]], 1);
}

// hierarchical scan: per-block local exclusive scan + block totals
__global__ __launch_bounds__(1024) void scan1(const int* __restrict__ deg,
                                              int* __restrict__ rowp,
                                              int* __restrict__ part) {
    __shared__ int buf[1024];
    int i = blockIdx.x * 1024 + threadIdx.x;
    int v = (i < N_NODES) ? deg[i] : 0;
    buf[threadIdx.x] = v;
    __syncthreads();
    for (int off = 1; off < 1024; off <<= 1) {
        int t = (threadIdx.x >= (unsigned)off) ? buf[threadIdx.x - off] : 0;
        __syncthreads();
        buf[threadIdx.x] += t;
        __syncthreads();
    }
    if (i < N_NODES) rowp[i] = buf[threadIdx.x] - v;   // local exclusive
    if (threadIdx.x == 1023) part[blockIdx.x] = buf[1023];
}

__global__ void scan2(int* __restrict__ part) {        // 1 block, 64 threads
    int v = (threadIdx.x < SCAN_BLOCKS) ? part[threadIdx.x] : 0;
    for (int off = 1; off < 64; off <<= 1) {
        int t = __shfl_up(v, off);
        if ((int)threadIdx.x >= off) v += t;
    }
    if (threadIdx.x < SCAN_BLOCKS) part[threadIdx.x] = v;   // inclusive totals
}

__global__ __launch_bounds__(1024) void scan3(int* __restrict__ rowp,
                                              const int* __restrict__ part) {
    int i = blockIdx.x * 1024 + threadIdx.x;
    int off = (blockIdx.x > 0) ? part[blockIdx.x - 1] : 0;
    if (i < N_NODES) rowp[i] += off;
    if (i == N_NODES) rowp[N_NODES] = part[SCAN_BLOCKS - 1];  // == N_EDGES
}

__global__ __launch_bounds__(256) void scatter_kernel(const int* __restrict__ src,
                                                      const int* __restrict__ dst,
                                                      const float* __restrict__ ew,
                                                      int* __restrict__ cursor,
                                                      int* __restrict__ csrc,
                                                      float* __restrict__ cw) {
    int e = blockIdx.x * 256 + threadIdx.x;
    if (e < N_EDGES) {
        int d = dst[e];
        int pos = atomicAdd(&cursor[d], 1);
        csrc[pos] = src[e];
        cw[pos] = ew[e];
    }
}

// ---------------- f32 -> bf16 row-major convert (for first GEMM's A) --------

__global__ __launch_bounds__(256) void cvt_kernel(const float* __restrict__ in,
                                                  unsigned short* __restrict__ out,
                                                  int n4) {
    int i = blockIdx.x * 256 + threadIdx.x;
    if (i >= n4) return;
    floatx4 v = *(const floatx4*)(in + (size_t)i * 4);
    ushort4 o;
    o.x = f32_to_bf16(v.x);
    o.y = f32_to_bf16(v.y);
    o.z = f32_to_bf16(v.z);
    o.w = f32_to_bf16(v.w);
    *(ushort4*)(out + (size_t)i * 4) = o;
}

// ---------------- fused SpMM + residual mix (feature-chunked bf16 gather) ----
// hC: [NCHUNK][N][CHUNK] bf16. For one chunk, working set = 50000*32*2B = 3.2MB
// -> fits per-XCD L2. Chunk index varies slowest in blockIdx.
// m = 0.9*(A@h) + 0.1*x0 ; writes mF (f32, exact residual) + mB (bf16 row-major)

__global__ __launch_bounds__(256) void spmm2(const unsigned short* __restrict__ hC,
                                             const float* __restrict__ x0,
                                             const int* __restrict__ rowp,
                                             const int* __restrict__ csrc,
                                             const float* __restrict__ cw,
                                             float* __restrict__ mF,
                                             unsigned short* __restrict__ mB) {
    int bc = blockIdx.x / SPMM_BLKS_PER_CHUNK;     // chunk, slowest
    int nb = blockIdx.x % SPMM_BLKS_PER_CHUNK;
    int v = nb * SPMM_NODES_PER_BLK + (threadIdx.x >> 5);
    int f = threadIdx.x & 31;
    const unsigned short* h = hC + (size_t)bc * N_NODES * CHUNK;
    int beg = rowp[v], end = rowp[v + 1];
    float acc = 0.f;
    for (int i = beg; i < end; i++) {
        int s = csrc[i];
        float w = cw[i];
        acc += w * bf16_to_f32(h[s * CHUNK + f]);
    }
    size_t off = (size_t)v * DIM + bc * CHUNK + f;
    float m = 0.9f * acc + 0.1f * x0[off];
    mF[off] = m;
    mB[off] = f32_to_bf16(m);
}

// ---------------- MFMA GEMM: out = relu(cm*Mres + cg*(A@W) + bias) ----------
// A: [N,128] bf16 row-major. W: [128,128] f32, cvt->bf16 into LDS^T.
// outF: optional f32 row-major. outC: optional chunked bf16 [NCHUNK][N][CHUNK].

__global__ __launch_bounds__(256) void gemm128(const unsigned short* __restrict__ A,
                                               const float* __restrict__ W,
                                               const float* __restrict__ Mres,
                                               const float* __restrict__ bias,
                                               float* __restrict__ outF,
                                               unsigned short* __restrict__ outC,
                                               float cm, float cg) {
    __shared__ unsigned short WT[128][136];   // transposed, +8 pad
    for (int idx = threadIdx.x; idx < 128 * 128; idx += 256) {
        int k = idx >> 7, n = idx & 127;
        WT[n][k] = f32_to_bf16(W[idx]);
    }
    __syncthreads();

    int wave = threadIdx.x >> 6;
    int lane = threadIdx.x & 63;
    int r0 = (blockIdx.x * 4 + wave) * 16;
    if (r0 >= N_NODES) return;                 // 16 | 50000, full tiles only

    int mrow = lane & 15;                      // A row within tile; also C col
    int quad = lane >> 4;

    floatx4 acc[8];
#pragma unroll
    for (int t = 0; t < 8; t++) acc[t] = {0.f, 0.f, 0.f, 0.f};

    const unsigned short* arow = A + (size_t)(r0 + mrow) * DIM;
#pragma unroll
    for (int k0 = 0; k0 < 128; k0 += 32) {
        short8 a = *(const short8*)(const void*)(arow + k0 + quad * 8);
#pragma unroll
        for (int t = 0; t < 8; t++) {
            short8 b = *(const short8*)(const void*)(&WT[t * 16 + mrow][k0 + quad * 8]);
            acc[t] = __builtin_amdgcn_mfma_f32_16x16x32_bf16(a, b, acc[t], 0, 0, 0);
        }
    }

    // C/D layout: col = lane&15, row = quad*4 + i  [verified m89/m91]
#pragma unroll
    for (int t = 0; t < 8; t++) {
        int col = t * 16 + mrow;
        float bv = bias ? bias[col] : 0.f;
#pragma unroll
        for (int i = 0; i < 4; i++) {
            int row = r0 + quad * 4 + i;
            size_t off = (size_t)row * DIM + col;
            float v = cg * acc[t][i] + bv;
            if (Mres) v += cm * Mres[off];
            v = fmaxf(v, 0.f);
            if (outF) outF[off] = v;
            if (outC) outC[((size_t)(col >> 5) * N_NODES + row) * CHUNK + (col & 31)]
                          = f32_to_bf16(v);
        }
    }
}

// ---------------- launch ----------------

extern "C" void kernel_launch(void* const* d_in, const int* in_sizes, int n_in,
                              void* d_out, int out_size, void* d_ws, size_t ws_size,
                              hipStream_t stream) {
    const float* x    = (const float*)d_in[0];
    const float* ew   = (const float*)d_in[1];
    const float* Wlin = (const float*)d_in[2];
    const float* blin = (const float*)d_in[3];
    const float* Wcv  = (const float*)d_in[4];
    const int* eidx = (const int*)d_in[5];
    const int* esrc = eidx;
    const int* edst = eidx + N_EDGES;
    float* out = (float*)d_out;

    char* ws = (char*)d_ws;
    float* x0F         = (float*)(ws);                       // 25.6 MB
    float* mF          = (float*)(ws + 25600000);            // 25.6 MB
    unsigned short* mB = (unsigned short*)(ws + 51200000);   // 12.8 MB (also bf16(x))
    unsigned short* x0C= (unsigned short*)(ws + 64000000);   // 12.8 MB chunked bf16 x0
    unsigned short* hC = (unsigned short*)(ws + 76800000);   // 12.8 MB chunked bf16 h
    int* rowp          = (int*)(ws + 89600000);              // (N+1)*4
    int* cursor        = (int*)(ws + 89800064);              // also 'deg'
    int* csrc          = (int*)(ws + 90000128);              // E*4
    float* cwt         = (float*)(ws + 93200128);            // E*4
    int* part          = (int*)(ws + 96400128);              // scan partials
    // total ~96.4 MB

    // CSR build (every call; no static state)
    (void)hipMemsetAsync(cursor, 0, (N_NODES + 1) * sizeof(int), stream);
    hist_kernel<<<(N_EDGES + 255) / 256, 256, 0, stream>>>(edst, cursor);
    scan1<<<SCAN_BLOCKS, 1024, 0, stream>>>(cursor, rowp, part);
    scan2<<<1, 64, 0, stream>>>(part);
    scan3<<<SCAN_BLOCKS, 1024, 0, stream>>>(rowp, part);
    (void)hipMemcpyAsync(cursor, rowp, N_NODES * sizeof(int), hipMemcpyDeviceToDevice, stream);
    scatter_kernel<<<(N_EDGES + 255) / 256, 256, 0, stream>>>(esrc, edst, ew, cursor, csrc, cwt);

    const int gemm_grid = (N_NODES + 63) / 64;   // 782

    // x -> bf16 (into mB), then x0 = relu(x @ W_lin + b_lin)  (f32 + chunked bf16)
    cvt_kernel<<<(N_NODES * DIM / 4 + 255) / 256, 256, 0, stream>>>(x, mB, N_NODES * DIM / 4);
    gemm128<<<gemm_grid, 256, 0, stream>>>(mB, Wlin, nullptr, blin, x0F, x0C, 0.f, 1.f);

    const unsigned short* hin = x0C;
    for (int l = 0; l < 8; l++) {
        spmm2<<<NCHUNK * SPMM_BLKS_PER_CHUNK, 256, 0, stream>>>(hin, x0F, rowp, csrc, cwt, mF, mB);
        float beta = logf(0.5f / (float)(l + 1) + 1.f);
        float* oF = (l == 7) ? out : nullptr;
        unsigned short* oC = (l < 7) ? hC : nullptr;
        gemm128<<<gemm_grid, 256, 0, stream>>>(mB, Wcv + (size_t)l * DIM * DIM, mF,
                                               nullptr, oF, oC, 1.f - beta, beta);
        hin = hC;
    }
}

// Round 5
// 883.981 us; speedup vs baseline: 1.8397x; 1.7983x over previous
//
#include <hip/hip_runtime.h>
#include <math.h>

#define N_NODES 50000
#define N_EDGES 800000
#define DIM 128
#define NCHUNK 4            // 128 features / 32
#define CHUNK 32
#define SPMM_NODES_PER_BLK 8
#define SPMM_BLKS_PER_CHUNK (N_NODES / SPMM_NODES_PER_BLK)   // 6250
#define SCAN_BLOCKS 49      // 49*1024 = 50176 >= 50001

typedef __attribute__((ext_vector_type(8))) short short8;
typedef __attribute__((ext_vector_type(4))) float floatx4;

// f32 -> bf16 bits, round-to-nearest-even (matches v_cvt / numpy)
__device__ __forceinline__ unsigned short f32_to_bf16(float f) {
    unsigned int u = __float_as_uint(f);
    u += 0x7fffu + ((u >> 16) & 1u);
    return (unsigned short)(u >> 16);
}
__device__ __forceinline__ float bf16_to_f32(unsigned short h) {
    return __uint_as_float((unsigned int)h << 16);
}

// ---------------- CSR build ----------------

__global__ __launch_bounds__(256) void hist_kernel(const int* __restrict__ dst,
                                                   int* __restrict__ deg) {
    int e = blockIdx.x * 256 + threadIdx.x;
    if (e < N_EDGES) atomicAdd(&deg[dst[e]], 1);
}

// hierarchical scan: per-block local exclusive scan + block totals
__global__ __launch_bounds__(1024) void scan1(const int* __restrict__ deg,
                                              int* __restrict__ rowp,
                                              int* __restrict__ part) {
    __shared__ int buf[1024];
    int i = blockIdx.x * 1024 + threadIdx.x;
    int v = (i < N_NODES) ? deg[i] : 0;
    buf[threadIdx.x] = v;
    __syncthreads();
    for (int off = 1; off < 1024; off <<= 1) {
        int t = (threadIdx.x >= (unsigned)off) ? buf[threadIdx.x - off] : 0;
        __syncthreads();
        buf[threadIdx.x] += t;
        __syncthreads();
    }
    if (i < N_NODES) rowp[i] = buf[threadIdx.x] - v;   // local exclusive
    if (threadIdx.x == 1023) part[blockIdx.x] = buf[1023];
}

__global__ void scan2(int* __restrict__ part) {        // 1 block, 64 threads
    int v = (threadIdx.x < SCAN_BLOCKS) ? part[threadIdx.x] : 0;
    for (int off = 1; off < 64; off <<= 1) {
        int t = __shfl_up(v, off);
        if ((int)threadIdx.x >= off) v += t;
    }
    if (threadIdx.x < SCAN_BLOCKS) part[threadIdx.x] = v;   // inclusive totals
}

__global__ __launch_bounds__(1024) void scan3(int* __restrict__ rowp,
                                              int* __restrict__ cursor,
                                              const int* __restrict__ part) {
    int i = blockIdx.x * 1024 + threadIdx.x;
    int off = (blockIdx.x > 0) ? part[blockIdx.x - 1] : 0;
    if (i < N_NODES) {
        int r = rowp[i] + off;
        rowp[i] = r;
        cursor[i] = r;           // scatter cursor starts at row begin
    }
    if (i == N_NODES) rowp[N_NODES] = part[SCAN_BLOCKS - 1];  // == N_EDGES
}

__global__ __launch_bounds__(256) void scatter_kernel(const int* __restrict__ src,
                                                      const int* __restrict__ dst,
                                                      const float* __restrict__ ew,
                                                      int* __restrict__ cursor,
                                                      int2* __restrict__ ep) {
    int e = blockIdx.x * 256 + threadIdx.x;
    if (e < N_EDGES) {
        int d = dst[e];
        int pos = atomicAdd(&cursor[d], 1);
        int2 p; p.x = src[e]; p.y = __float_as_int(ew[e]);
        ep[pos] = p;
    }
}

// ---------------- f32 -> bf16 row-major convert (for first GEMM's A) --------

__global__ __launch_bounds__(256) void cvt_kernel(const float* __restrict__ in,
                                                  unsigned short* __restrict__ out,
                                                  int n4) {
    int i = blockIdx.x * 256 + threadIdx.x;
    if (i >= n4) return;
    floatx4 v = *(const floatx4*)(in + (size_t)i * 4);
    ushort4 o;
    o.x = f32_to_bf16(v.x);
    o.y = f32_to_bf16(v.y);
    o.z = f32_to_bf16(v.z);
    o.w = f32_to_bf16(v.w);
    *(ushort4*)(out + (size_t)i * 4) = o;
}

// ---------------- fused SpMM + residual mix (chunked bf16 gather, ILP-8) ----
// hC/x0C: [NCHUNK][N][CHUNK] bf16; per-chunk working set 3.2MB fits per-XCD L2.
// Edge data packed int2{src, w_bits} -> one 8B load/edge, 8-deep unroll for
// 8 independent gathers in flight (was: serial 2-load chain per edge).

#define GATH(e) bf16_to_f32(h[((e).x << 5) | f])
#define ACC(e, g) acc = fmaf(__int_as_float((e).y), (g), acc)

__global__ __launch_bounds__(256) void spmm3(const unsigned short* __restrict__ hC,
                                             const unsigned short* __restrict__ x0C,
                                             const int* __restrict__ rowp,
                                             const int2* __restrict__ ep,
                                             float* __restrict__ mF,
                                             unsigned short* __restrict__ mB) {
    int bc = blockIdx.x / SPMM_BLKS_PER_CHUNK;     // chunk, slowest
    int nb = blockIdx.x % SPMM_BLKS_PER_CHUNK;
    int v = nb * SPMM_NODES_PER_BLK + (threadIdx.x >> 5);
    int f = threadIdx.x & 31;
    const unsigned short* h = hC + (size_t)bc * N_NODES * CHUNK;
    int beg = rowp[v], end = rowp[v + 1];
    float acc = 0.f;
    int i = beg;
    for (; i + 8 <= end; i += 8) {
        int2 e0 = ep[i], e1 = ep[i+1], e2 = ep[i+2], e3 = ep[i+3];
        int2 e4 = ep[i+4], e5 = ep[i+5], e6 = ep[i+6], e7 = ep[i+7];
        float g0 = GATH(e0), g1 = GATH(e1), g2 = GATH(e2), g3 = GATH(e3);
        float g4 = GATH(e4), g5 = GATH(e5), g6 = GATH(e6), g7 = GATH(e7);
        ACC(e0, g0); ACC(e1, g1); ACC(e2, g2); ACC(e3, g3);
        ACC(e4, g4); ACC(e5, g5); ACC(e6, g6); ACC(e7, g7);
    }
    if (i + 4 <= end) {
        int2 e0 = ep[i], e1 = ep[i+1], e2 = ep[i+2], e3 = ep[i+3];
        float g0 = GATH(e0), g1 = GATH(e1), g2 = GATH(e2), g3 = GATH(e3);
        ACC(e0, g0); ACC(e1, g1); ACC(e2, g2); ACC(e3, g3);
        i += 4;
    }
    for (; i < end; i++) {
        int2 e = ep[i];
        float g = GATH(e);
        ACC(e, g);
    }
    size_t coff = ((size_t)bc * N_NODES + v) * CHUNK + f;
    float m = 0.9f * acc + 0.1f * bf16_to_f32(x0C[coff]);
    size_t off = (size_t)v * DIM + bc * CHUNK + f;
    mF[off] = m;
    mB[off] = f32_to_bf16(m);
}

// ---------------- MFMA GEMM: out = relu(cm*Mres + cg*(A@W) + bias) ----------
// A: [N,128] bf16 row-major. W: [128,128] f32, cvt->bf16 into LDS^T.
// outF: optional f32 row-major. outC: optional chunked bf16 [NCHUNK][N][CHUNK].

__global__ __launch_bounds__(256) void gemm128(const unsigned short* __restrict__ A,
                                               const float* __restrict__ W,
                                               const float* __restrict__ Mres,
                                               const float* __restrict__ bias,
                                               float* __restrict__ outF,
                                               unsigned short* __restrict__ outC,
                                               float cm, float cg) {
    __shared__ unsigned short WT[128][136];   // transposed, +8 pad
    for (int idx = threadIdx.x; idx < 128 * 128; idx += 256) {
        int k = idx >> 7, n = idx & 127;
        WT[n][k] = f32_to_bf16(W[idx]);
    }
    __syncthreads();

    int wave = threadIdx.x >> 6;
    int lane = threadIdx.x & 63;
    int r0 = (blockIdx.x * 4 + wave) * 16;
    if (r0 >= N_NODES) return;                 // 16 | 50000, full tiles only

    int mrow = lane & 15;                      // A row within tile; also C col
    int quad = lane >> 4;

    floatx4 acc[8];
#pragma unroll
    for (int t = 0; t < 8; t++) acc[t] = {0.f, 0.f, 0.f, 0.f};

    const unsigned short* arow = A + (size_t)(r0 + mrow) * DIM;
#pragma unroll
    for (int k0 = 0; k0 < 128; k0 += 32) {
        short8 a = *(const short8*)(const void*)(arow + k0 + quad * 8);
#pragma unroll
        for (int t = 0; t < 8; t++) {
            short8 b = *(const short8*)(const void*)(&WT[t * 16 + mrow][k0 + quad * 8]);
            acc[t] = __builtin_amdgcn_mfma_f32_16x16x32_bf16(a, b, acc[t], 0, 0, 0);
        }
    }

    // C/D layout: col = lane&15, row = quad*4 + i  [verified m89/m91]
#pragma unroll
    for (int t = 0; t < 8; t++) {
        int col = t * 16 + mrow;
        float bv = bias ? bias[col] : 0.f;
#pragma unroll
        for (int i = 0; i < 4; i++) {
            int row = r0 + quad * 4 + i;
            size_t off = (size_t)row * DIM + col;
            float v = cg * acc[t][i] + bv;
            if (Mres) v += cm * Mres[off];
            v = fmaxf(v, 0.f);
            if (outF) outF[off] = v;
            if (outC) outC[((size_t)(col >> 5) * N_NODES + row) * CHUNK + (col & 31)]
                          = f32_to_bf16(v);
        }
    }
}

// ---------------- launch ----------------

extern "C" void kernel_launch(void* const* d_in, const int* in_sizes, int n_in,
                              void* d_out, int out_size, void* d_ws, size_t ws_size,
                              hipStream_t stream) {
    const float* x    = (const float*)d_in[0];
    const float* ew   = (const float*)d_in[1];
    const float* Wlin = (const float*)d_in[2];
    const float* blin = (const float*)d_in[3];
    const float* Wcv  = (const float*)d_in[4];
    const int* eidx = (const int*)d_in[5];
    const int* esrc = eidx;
    const int* edst = eidx + N_EDGES;
    float* out = (float*)d_out;

    char* ws = (char*)d_ws;
    float* x0F         = (float*)(ws);                       // 25.6 MB (first GEMM f32 out; unused after)
    float* mF          = (float*)(ws + 25600000);            // 25.6 MB
    unsigned short* mB = (unsigned short*)(ws + 51200000);   // 12.8 MB (also bf16(x))
    unsigned short* x0C= (unsigned short*)(ws + 64000000);   // 12.8 MB chunked bf16 x0
    unsigned short* hC = (unsigned short*)(ws + 76800000);   // 12.8 MB chunked bf16 h
    int* rowp          = (int*)(ws + 89600000);              // (N+1)*4
    int* cursor        = (int*)(ws + 89800064);              // also 'deg'
    int2* epack        = (int2*)(ws + 90000128);             // E*8
    int* part          = (int*)(ws + 96400128);              // scan partials
    // total ~96.4 MB

    // CSR build (every call; no static state)
    (void)hipMemsetAsync(cursor, 0, (N_NODES + 1) * sizeof(int), stream);
    hist_kernel<<<(N_EDGES + 255) / 256, 256, 0, stream>>>(edst, cursor);
    scan1<<<SCAN_BLOCKS, 1024, 0, stream>>>(cursor, rowp, part);
    scan2<<<1, 64, 0, stream>>>(part);
    scan3<<<SCAN_BLOCKS, 1024, 0, stream>>>(rowp, cursor, part);
    scatter_kernel<<<(N_EDGES + 255) / 256, 256, 0, stream>>>(esrc, edst, ew, cursor, epack);

    const int gemm_grid = (N_NODES + 63) / 64;   // 782

    // x -> bf16 (into mB), then x0 = relu(x @ W_lin + b_lin)  (chunked bf16 out)
    cvt_kernel<<<(N_NODES * DIM / 4 + 255) / 256, 256, 0, stream>>>(x, mB, N_NODES * DIM / 4);
    gemm128<<<gemm_grid, 256, 0, stream>>>(mB, Wlin, nullptr, blin, x0F, x0C, 0.f, 1.f);

    const unsigned short* hin = x0C;
    for (int l = 0; l < 8; l++) {
        spmm3<<<NCHUNK * SPMM_BLKS_PER_CHUNK, 256, 0, stream>>>(hin, x0C, rowp, epack, mF, mB);
        float beta = logf(0.5f / (float)(l + 1) + 1.f);
        float* oF = (l == 7) ? out : nullptr;
        unsigned short* oC = (l < 7) ? hC : nullptr;
        gemm128<<<gemm_grid, 256, 0, stream>>>(mB, Wcv + (size_t)l * DIM * DIM, mF,
                                               nullptr, oF, oC, 1.f - beta, beta);
        hin = hC;
    }
}

// Round 6
// 741.604 us; speedup vs baseline: 2.1929x; 1.1920x over previous
//
#include <hip/hip_runtime.h>
#include <math.h>

#define N_NODES 50000
#define N_EDGES 800000
#define DIM 128
#define NCHUNK 4            // 128 features / 32
#define CHUNK 32
#define SCAN_BLOCKS 49      // 49*1024 = 50176 >= 50001
#define SPMM_NPB 64         // nodes per block (256 thr / 4 lanes-per-node)
#define SPMM_NBLK ((N_NODES + SPMM_NPB - 1) / SPMM_NPB)   // 782

typedef __attribute__((ext_vector_type(8))) short short8;
typedef __attribute__((ext_vector_type(4))) float floatx4;

// f32 -> bf16 bits, round-to-nearest-even (matches v_cvt / numpy)
__device__ __forceinline__ unsigned short f32_to_bf16(float f) {
    unsigned int u = __float_as_uint(f);
    u += 0x7fffu + ((u >> 16) & 1u);
    return (unsigned short)(u >> 16);
}
__device__ __forceinline__ float bf16_to_f32(unsigned short h) {
    return __uint_as_float((unsigned int)h << 16);
}

// ---------------- CSR build ----------------

__global__ __launch_bounds__(256) void hist_kernel(const int* __restrict__ dst,
                                                   int* __restrict__ deg) {
    int e = blockIdx.x * 256 + threadIdx.x;
    if (e < N_EDGES) atomicAdd(&deg[dst[e]], 1);
}

__global__ __launch_bounds__(1024) void scan1(const int* __restrict__ deg,
                                              int* __restrict__ rowp,
                                              int* __restrict__ part) {
    __shared__ int buf[1024];
    int i = blockIdx.x * 1024 + threadIdx.x;
    int v = (i < N_NODES) ? deg[i] : 0;
    buf[threadIdx.x] = v;
    __syncthreads();
    for (int off = 1; off < 1024; off <<= 1) {
        int t = (threadIdx.x >= (unsigned)off) ? buf[threadIdx.x - off] : 0;
        __syncthreads();
        buf[threadIdx.x] += t;
        __syncthreads();
    }
    if (i < N_NODES) rowp[i] = buf[threadIdx.x] - v;   // local exclusive
    if (threadIdx.x == 1023) part[blockIdx.x] = buf[1023];
}

__global__ void scan2(int* __restrict__ part) {        // 1 block, 64 threads
    int v = (threadIdx.x < SCAN_BLOCKS) ? part[threadIdx.x] : 0;
    for (int off = 1; off < 64; off <<= 1) {
        int t = __shfl_up(v, off);
        if ((int)threadIdx.x >= off) v += t;
    }
    if (threadIdx.x < SCAN_BLOCKS) part[threadIdx.x] = v;   // inclusive totals
}

__global__ __launch_bounds__(1024) void scan3(int* __restrict__ rowp,
                                              int* __restrict__ cursor,
                                              const int* __restrict__ part) {
    int i = blockIdx.x * 1024 + threadIdx.x;
    int off = (blockIdx.x > 0) ? part[blockIdx.x - 1] : 0;
    if (i < N_NODES) {
        int r = rowp[i] + off;
        rowp[i] = r;
        cursor[i] = r;
    }
    if (i == N_NODES) rowp[N_NODES] = part[SCAN_BLOCKS - 1];  // == N_EDGES
}

__global__ __launch_bounds__(256) void scatter_kernel(const int* __restrict__ src,
                                                      const int* __restrict__ dst,
                                                      const float* __restrict__ ew,
                                                      int* __restrict__ cursor,
                                                      int2* __restrict__ ep) {
    int e = blockIdx.x * 256 + threadIdx.x;
    if (e < N_EDGES) {
        int d = dst[e];
        int pos = atomicAdd(&cursor[d], 1);
        int2 p; p.x = src[e]; p.y = __float_as_int(ew[e]);
        ep[pos] = p;
    }
}

// ---------------- fused SpMM + residual mix (16B gathers, 4 lanes/node) -----
// hC/x0C: [NCHUNK][N][CHUNK] bf16. thread = (node, 8-feature octet).
// Per edge: one 16B dwordx4 gather (8 bf16) instead of 8x 2B gathers -> 8x
// fewer TA address cycles. Unroll-4 keeps 4 gathers in flight per thread.

__global__ __launch_bounds__(256) void spmm4(const unsigned short* __restrict__ hC,
                                             const unsigned short* __restrict__ x0C,
                                             const int* __restrict__ rowp,
                                             const int2* __restrict__ ep,
                                             float* __restrict__ mF) {
    int blk = blockIdx.x;
    int bc = blk / SPMM_NBLK;                       // chunk, slowest
    int nb = blk % SPMM_NBLK;
    int node = nb * SPMM_NPB + (threadIdx.x >> 2);
    int oct = (threadIdx.x & 3) * 8;                // feature offset in chunk
    if (node >= N_NODES) return;
    const unsigned short* h = hC + (size_t)bc * (N_NODES * CHUNK);
    int beg = rowp[node], end = rowp[node + 1];
    float acc[8] = {0.f, 0.f, 0.f, 0.f, 0.f, 0.f, 0.f, 0.f};
    int i = beg;
    for (; i + 4 <= end; i += 4) {
        int2 e0 = ep[i], e1 = ep[i + 1], e2 = ep[i + 2], e3 = ep[i + 3];
        short8 r0 = *(const short8*)(const void*)(h + e0.x * CHUNK + oct);
        short8 r1 = *(const short8*)(const void*)(h + e1.x * CHUNK + oct);
        short8 r2 = *(const short8*)(const void*)(h + e2.x * CHUNK + oct);
        short8 r3 = *(const short8*)(const void*)(h + e3.x * CHUNK + oct);
        float w0 = __int_as_float(e0.y), w1 = __int_as_float(e1.y);
        float w2 = __int_as_float(e2.y), w3 = __int_as_float(e3.y);
#pragma unroll
        for (int j = 0; j < 8; j++) {
            acc[j] = fmaf(w0, bf16_to_f32((unsigned short)r0[j]), acc[j]);
            acc[j] = fmaf(w1, bf16_to_f32((unsigned short)r1[j]), acc[j]);
            acc[j] = fmaf(w2, bf16_to_f32((unsigned short)r2[j]), acc[j]);
            acc[j] = fmaf(w3, bf16_to_f32((unsigned short)r3[j]), acc[j]);
        }
    }
    for (; i < end; i++) {
        int2 e = ep[i];
        short8 r = *(const short8*)(const void*)(h + e.x * CHUNK + oct);
        float w = __int_as_float(e.y);
#pragma unroll
        for (int j = 0; j < 8; j++)
            acc[j] = fmaf(w, bf16_to_f32((unsigned short)r[j]), acc[j]);
    }
    size_t coff = ((size_t)bc * N_NODES + node) * CHUNK + oct;
    size_t off  = (size_t)node * DIM + bc * CHUNK + oct;
    short8 xr = *(const short8*)(const void*)(x0C + coff);
    floatx4 o0, o1;
#pragma unroll
    for (int j = 0; j < 4; j++)
        o0[j] = 0.9f * acc[j] + 0.1f * bf16_to_f32((unsigned short)xr[j]);
#pragma unroll
    for (int j = 0; j < 4; j++)
        o1[j] = 0.9f * acc[4 + j] + 0.1f * bf16_to_f32((unsigned short)xr[4 + j]);
    *(floatx4*)(mF + off) = o0;
    *(floatx4*)(mF + off + 4) = o1;
}

// ---------------- MFMA GEMM: out = relu(cm*Mres + cg*(A@W) + bias) ----------
// A: [N,128] f32 row-major, cvt->bf16 in-register (A and Mres may be the SAME
// buffer -> one HBM read). W: [128,128] f32, cvt->bf16 into LDS^T.
// outF: optional f32 row-major. outC: optional chunked bf16 [NCHUNK][N][CHUNK].

__global__ __launch_bounds__(256) void gemm128(const float* __restrict__ A,
                                               const float* __restrict__ W,
                                               const float* __restrict__ Mres,
                                               const float* __restrict__ bias,
                                               float* __restrict__ outF,
                                               unsigned short* __restrict__ outC,
                                               float cm, float cg) {
    __shared__ unsigned short WT[128][136];   // transposed, +8 pad
    for (int idx = threadIdx.x; idx < 128 * 128; idx += 256) {
        int k = idx >> 7, n = idx & 127;
        WT[n][k] = f32_to_bf16(W[idx]);
    }
    __syncthreads();

    int wave = threadIdx.x >> 6;
    int lane = threadIdx.x & 63;
    int r0 = (blockIdx.x * 4 + wave) * 16;
    if (r0 >= N_NODES) return;                 // 16 | 50000, full tiles only

    int mrow = lane & 15;                      // A row within tile; also C col
    int quad = lane >> 4;

    floatx4 acc[8];
#pragma unroll
    for (int t = 0; t < 8; t++) acc[t] = {0.f, 0.f, 0.f, 0.f};

    const float* arow = A + (size_t)(r0 + mrow) * DIM;
#pragma unroll
    for (int k0 = 0; k0 < 128; k0 += 32) {
        floatx4 alo = *(const floatx4*)(const void*)(arow + k0 + quad * 8);
        floatx4 ahi = *(const floatx4*)(const void*)(arow + k0 + quad * 8 + 4);
        short8 a;
#pragma unroll
        for (int j = 0; j < 4; j++) a[j] = (short)f32_to_bf16(alo[j]);
#pragma unroll
        for (int j = 0; j < 4; j++) a[4 + j] = (short)f32_to_bf16(ahi[j]);
#pragma unroll
        for (int t = 0; t < 8; t++) {
            short8 b = *(const short8*)(const void*)(&WT[t * 16 + mrow][k0 + quad * 8]);
            acc[t] = __builtin_amdgcn_mfma_f32_16x16x32_bf16(a, b, acc[t], 0, 0, 0);
        }
    }

    // C/D layout: col = lane&15, row = quad*4 + i  [verified m89/m91]
#pragma unroll
    for (int t = 0; t < 8; t++) {
        int col = t * 16 + mrow;
        float bv = bias ? bias[col] : 0.f;
#pragma unroll
        for (int i = 0; i < 4; i++) {
            int row = r0 + quad * 4 + i;
            size_t off = (size_t)row * DIM + col;
            float v = cg * acc[t][i] + bv;
            if (Mres) v += cm * Mres[off];
            v = fmaxf(v, 0.f);
            if (outF) outF[off] = v;
            if (outC) outC[((size_t)(col >> 5) * N_NODES + row) * CHUNK + (col & 31)]
                          = f32_to_bf16(v);
        }
    }
}

// ---------------- launch ----------------

extern "C" void kernel_launch(void* const* d_in, const int* in_sizes, int n_in,
                              void* d_out, int out_size, void* d_ws, size_t ws_size,
                              hipStream_t stream) {
    const float* x    = (const float*)d_in[0];
    const float* ew   = (const float*)d_in[1];
    const float* Wlin = (const float*)d_in[2];
    const float* blin = (const float*)d_in[3];
    const float* Wcv  = (const float*)d_in[4];
    const int* eidx = (const int*)d_in[5];
    const int* esrc = eidx;
    const int* edst = eidx + N_EDGES;
    float* out = (float*)d_out;

    char* ws = (char*)d_ws;
    float* mF          = (float*)(ws);                       // 25.6 MB (spmm out, gemm A+Mres)
    unsigned short* x0C= (unsigned short*)(ws + 25600000);   // 12.8 MB chunked bf16 x0
    unsigned short* hC = (unsigned short*)(ws + 38400000);   // 12.8 MB chunked bf16 h
    int* rowp          = (int*)(ws + 51200000);              // (N+1)*4
    int* cursor        = (int*)(ws + 51400064);              // also 'deg'
    int2* epack        = (int2*)(ws + 51600128);             // E*8
    int* part          = (int*)(ws + 58000128);              // scan partials
    // total ~58 MB

    // CSR build (every call; no static state)
    (void)hipMemsetAsync(cursor, 0, (N_NODES + 1) * sizeof(int), stream);
    hist_kernel<<<(N_EDGES + 255) / 256, 256, 0, stream>>>(edst, cursor);
    scan1<<<SCAN_BLOCKS, 1024, 0, stream>>>(cursor, rowp, part);
    scan2<<<1, 64, 0, stream>>>(part);
    scan3<<<SCAN_BLOCKS, 1024, 0, stream>>>(rowp, cursor, part);
    scatter_kernel<<<(N_EDGES + 255) / 256, 256, 0, stream>>>(esrc, edst, ew, cursor, epack);

    const int gemm_grid = (N_NODES + 63) / 64;   // 782

    // x0 = relu(x @ W_lin + b_lin) -> chunked bf16 (x read as f32 directly)
    gemm128<<<gemm_grid, 256, 0, stream>>>(x, Wlin, nullptr, blin, nullptr, x0C, 0.f, 1.f);

    const unsigned short* hin = x0C;
    for (int l = 0; l < 8; l++) {
        spmm4<<<NCHUNK * SPMM_NBLK, 256, 0, stream>>>(hin, x0C, rowp, epack, mF);
        float beta = logf(0.5f / (float)(l + 1) + 1.f);
        float* oF = (l == 7) ? out : nullptr;
        unsigned short* oC = (l < 7) ? hC : nullptr;
        gemm128<<<gemm_grid, 256, 0, stream>>>(mF, Wcv + (size_t)l * DIM * DIM, mF,
                                               nullptr, oF, oC, 1.f - beta, beta);
        hin = hC;
    }
}

// Round 7
// 603.554 us; speedup vs baseline: 2.6945x; 1.2287x over previous
//
#include <hip/hip_runtime.h>
#include <math.h>

#define N_NODES 50000
#define N_EDGES 800000
#define DIM 128
#define SCAN_BLOCKS 49      // 49*1024 = 50176 >= 50001

typedef __attribute__((ext_vector_type(8))) short short8;
typedef __attribute__((ext_vector_type(4))) float floatx4;

// f32 -> bf16 bits, round-to-nearest-even (matches v_cvt / numpy)
__device__ __forceinline__ unsigned short f32_to_bf16(float f) {
    unsigned int u = __float_as_uint(f);
    u += 0x7fffu + ((u >> 16) & 1u);
    return (unsigned short)(u >> 16);
}
__device__ __forceinline__ float bf16_to_f32(unsigned short h) {
    return __uint_as_float((unsigned int)h << 16);
}

// ---------------- CSR build ----------------

__global__ __launch_bounds__(256) void hist_kernel(const int* __restrict__ dst,
                                                   int* __restrict__ deg) {
    int e = blockIdx.x * 256 + threadIdx.x;
    if (e < N_EDGES) atomicAdd(&deg[dst[e]], 1);
}

__global__ __launch_bounds__(1024) void scan1(const int* __restrict__ deg,
                                              int* __restrict__ rowp,
                                              int* __restrict__ part) {
    __shared__ int buf[1024];
    int i = blockIdx.x * 1024 + threadIdx.x;
    int v = (i < N_NODES) ? deg[i] : 0;
    buf[threadIdx.x] = v;
    __syncthreads();
    for (int off = 1; off < 1024; off <<= 1) {
        int t = (threadIdx.x >= (unsigned)off) ? buf[threadIdx.x - off] : 0;
        __syncthreads();
        buf[threadIdx.x] += t;
        __syncthreads();
    }
    if (i < N_NODES) rowp[i] = buf[threadIdx.x] - v;   // local exclusive
    if (threadIdx.x == 1023) part[blockIdx.x] = buf[1023];
}

__global__ void scan2(int* __restrict__ part) {        // 1 block, 64 threads
    int v = (threadIdx.x < SCAN_BLOCKS) ? part[threadIdx.x] : 0;
    for (int off = 1; off < 64; off <<= 1) {
        int t = __shfl_up(v, off);
        if ((int)threadIdx.x >= off) v += t;
    }
    if (threadIdx.x < SCAN_BLOCKS) part[threadIdx.x] = v;   // inclusive totals
}

__global__ __launch_bounds__(1024) void scan3(int* __restrict__ rowp,
                                              int* __restrict__ cursor,
                                              const int* __restrict__ part) {
    int i = blockIdx.x * 1024 + threadIdx.x;
    int off = (blockIdx.x > 0) ? part[blockIdx.x - 1] : 0;
    if (i < N_NODES) {
        int r = rowp[i] + off;
        rowp[i] = r;
        cursor[i] = r;
    }
    if (i == N_NODES) rowp[N_NODES] = part[SCAN_BLOCKS - 1];  // == N_EDGES
}

__global__ __launch_bounds__(256) void scatter_kernel(const int* __restrict__ src,
                                                      const int* __restrict__ dst,
                                                      const float* __restrict__ ew,
                                                      int* __restrict__ cursor,
                                                      int2* __restrict__ ep) {
    int e = blockIdx.x * 256 + threadIdx.x;
    if (e < N_EDGES) {
        int d = dst[e];
        int pos = atomicAdd(&cursor[d], 1);
        int2 p; p.x = src[e]; p.y = __float_as_int(ew[e]);
        ep[pos] = p;
    }
}

// ---------------- fused SpMM + residual mix (row-major bf16, 4 lanes/node) --
// hB/x0B/mB: [N][128] bf16 row-major. thread = (node, 32-feature quarter).
// Per edge a thread issues 4 contiguous 16B gathers (one 64B line); the 4
// threads of a node cover the full 256B row -> full line utilization.
// ILP-2 over edges keeps 8 gathers in flight. h (12.8MB) is L2/L3-resident.

__global__ __launch_bounds__(256) void spmm5(const unsigned short* __restrict__ hB,
                                             const unsigned short* __restrict__ x0B,
                                             const int* __restrict__ rowp,
                                             const int2* __restrict__ ep,
                                             unsigned short* __restrict__ mB) {
    int node = blockIdx.x * 64 + (threadIdx.x >> 2);
    if (node >= N_NODES) return;
    int fb = (threadIdx.x & 3) * 32;               // feature base
    int beg = rowp[node], end = rowp[node + 1];
    float acc[32];
#pragma unroll
    for (int j = 0; j < 32; j++) acc[j] = 0.f;
    int i = beg;
    for (; i + 2 <= end; i += 2) {
        int2 e0 = ep[i], e1 = ep[i + 1];
        const unsigned short* r0 = hB + (size_t)e0.x * DIM + fb;
        const unsigned short* r1 = hB + (size_t)e1.x * DIM + fb;
        short8 a0 = *(const short8*)(const void*)(r0);
        short8 a1 = *(const short8*)(const void*)(r0 + 8);
        short8 a2 = *(const short8*)(const void*)(r0 + 16);
        short8 a3 = *(const short8*)(const void*)(r0 + 24);
        short8 b0 = *(const short8*)(const void*)(r1);
        short8 b1 = *(const short8*)(const void*)(r1 + 8);
        short8 b2 = *(const short8*)(const void*)(r1 + 16);
        short8 b3 = *(const short8*)(const void*)(r1 + 24);
        float w0 = __int_as_float(e0.y), w1 = __int_as_float(e1.y);
#pragma unroll
        for (int j = 0; j < 8; j++) {
            acc[j]      = fmaf(w0, bf16_to_f32((unsigned short)a0[j]), acc[j]);
            acc[8 + j]  = fmaf(w0, bf16_to_f32((unsigned short)a1[j]), acc[8 + j]);
            acc[16 + j] = fmaf(w0, bf16_to_f32((unsigned short)a2[j]), acc[16 + j]);
            acc[24 + j] = fmaf(w0, bf16_to_f32((unsigned short)a3[j]), acc[24 + j]);
            acc[j]      = fmaf(w1, bf16_to_f32((unsigned short)b0[j]), acc[j]);
            acc[8 + j]  = fmaf(w1, bf16_to_f32((unsigned short)b1[j]), acc[8 + j]);
            acc[16 + j] = fmaf(w1, bf16_to_f32((unsigned short)b2[j]), acc[16 + j]);
            acc[24 + j] = fmaf(w1, bf16_to_f32((unsigned short)b3[j]), acc[24 + j]);
        }
    }
    if (i < end) {
        int2 e0 = ep[i];
        const unsigned short* r0 = hB + (size_t)e0.x * DIM + fb;
        short8 a0 = *(const short8*)(const void*)(r0);
        short8 a1 = *(const short8*)(const void*)(r0 + 8);
        short8 a2 = *(const short8*)(const void*)(r0 + 16);
        short8 a3 = *(const short8*)(const void*)(r0 + 24);
        float w0 = __int_as_float(e0.y);
#pragma unroll
        for (int j = 0; j < 8; j++) {
            acc[j]      = fmaf(w0, bf16_to_f32((unsigned short)a0[j]), acc[j]);
            acc[8 + j]  = fmaf(w0, bf16_to_f32((unsigned short)a1[j]), acc[8 + j]);
            acc[16 + j] = fmaf(w0, bf16_to_f32((unsigned short)a2[j]), acc[16 + j]);
            acc[24 + j] = fmaf(w0, bf16_to_f32((unsigned short)a3[j]), acc[24 + j]);
        }
    }
    // m = 0.9*agg + 0.1*x0  -> bf16
    const unsigned short* xr = x0B + (size_t)node * DIM + fb;
    unsigned short* mw = mB + (size_t)node * DIM + fb;
#pragma unroll
    for (int q = 0; q < 4; q++) {
        short8 xv = *(const short8*)(const void*)(xr + q * 8);
        short8 o;
#pragma unroll
        for (int j = 0; j < 8; j++)
            o[j] = (short)f32_to_bf16(0.9f * acc[q * 8 + j]
                                      + 0.1f * bf16_to_f32((unsigned short)xv[j]));
        *(short8*)(void*)(mw + q * 8) = o;
    }
}

// ---------------- MFMA GEMM: out = relu(A @ (cg*W + cm*I) + bias) -----------
// Residual is FOLDED into the weight during LDS staging: W'[k][n] = cg*W + cm*I,
// so out = cg*(A@W) + cm*A in one MFMA pass — no separate f32 residual stream.
// A: [N,128] row-major, f32 (AF32=true) or bf16. outF f32 / outB bf16 optional.

template <bool AF32>
__global__ __launch_bounds__(256) void gemm128(const void* __restrict__ Av,
                                               const float* __restrict__ W,
                                               const float* __restrict__ bias,
                                               float* __restrict__ outF,
                                               unsigned short* __restrict__ outB,
                                               float cm, float cg) {
    __shared__ unsigned short WT[128][136];   // transposed, +8 pad
    for (int idx = threadIdx.x; idx < 128 * 128; idx += 256) {
        int k = idx >> 7, n = idx & 127;
        float wv = cg * W[idx] + ((n == k) ? cm : 0.f);
        WT[n][k] = f32_to_bf16(wv);
    }
    __syncthreads();

    int wave = threadIdx.x >> 6;
    int lane = threadIdx.x & 63;
    int r0 = (blockIdx.x * 4 + wave) * 16;
    if (r0 >= N_NODES) return;                 // 16 | 50000, full tiles only

    int mrow = lane & 15;                      // A row within tile; also C col
    int quad = lane >> 4;

    floatx4 acc[8];
#pragma unroll
    for (int t = 0; t < 8; t++) acc[t] = {0.f, 0.f, 0.f, 0.f};

#pragma unroll
    for (int k0 = 0; k0 < 128; k0 += 32) {
        short8 a;
        if constexpr (AF32) {
            const float* arow = (const float*)Av + (size_t)(r0 + mrow) * DIM;
            floatx4 alo = *(const floatx4*)(const void*)(arow + k0 + quad * 8);
            floatx4 ahi = *(const floatx4*)(const void*)(arow + k0 + quad * 8 + 4);
#pragma unroll
            for (int j = 0; j < 4; j++) a[j] = (short)f32_to_bf16(alo[j]);
#pragma unroll
            for (int j = 0; j < 4; j++) a[4 + j] = (short)f32_to_bf16(ahi[j]);
        } else {
            const unsigned short* arow = (const unsigned short*)Av + (size_t)(r0 + mrow) * DIM;
            a = *(const short8*)(const void*)(arow + k0 + quad * 8);
        }
#pragma unroll
        for (int t = 0; t < 8; t++) {
            short8 b = *(const short8*)(const void*)(&WT[t * 16 + mrow][k0 + quad * 8]);
            acc[t] = __builtin_amdgcn_mfma_f32_16x16x32_bf16(a, b, acc[t], 0, 0, 0);
        }
    }

    // C/D layout: col = lane&15, row = quad*4 + i  [verified m89/m91]
#pragma unroll
    for (int t = 0; t < 8; t++) {
        int col = t * 16 + mrow;
        float bv = bias ? bias[col] : 0.f;
#pragma unroll
        for (int i = 0; i < 4; i++) {
            int row = r0 + quad * 4 + i;
            size_t off = (size_t)row * DIM + col;
            float v = fmaxf(acc[t][i] + bv, 0.f);
            if (outF) outF[off] = v;
            if (outB) outB[off] = f32_to_bf16(v);
        }
    }
}

// ---------------- launch ----------------

extern "C" void kernel_launch(void* const* d_in, const int* in_sizes, int n_in,
                              void* d_out, int out_size, void* d_ws, size_t ws_size,
                              hipStream_t stream) {
    const float* x    = (const float*)d_in[0];
    const float* ew   = (const float*)d_in[1];
    const float* Wlin = (const float*)d_in[2];
    const float* blin = (const float*)d_in[3];
    const float* Wcv  = (const float*)d_in[4];
    const int* eidx = (const int*)d_in[5];
    const int* esrc = eidx;
    const int* edst = eidx + N_EDGES;
    float* out = (float*)d_out;

    char* ws = (char*)d_ws;
    unsigned short* x0B = (unsigned short*)(ws);             // 12.8 MB bf16 x0 rows
    unsigned short* mB  = (unsigned short*)(ws + 12800000);  // 12.8 MB bf16 m rows
    unsigned short* hB  = (unsigned short*)(ws + 25600000);  // 12.8 MB bf16 h rows
    int* rowp           = (int*)(ws + 38400000);             // (N+1)*4
    int* cursor         = (int*)(ws + 38600064);             // also 'deg'
    int2* epack         = (int2*)(ws + 38800128);            // E*8
    int* part           = (int*)(ws + 45200128);             // scan partials
    // total ~45.2 MB

    // CSR build (every call; no static state)
    (void)hipMemsetAsync(cursor, 0, (N_NODES + 1) * sizeof(int), stream);
    hist_kernel<<<(N_EDGES + 255) / 256, 256, 0, stream>>>(edst, cursor);
    scan1<<<SCAN_BLOCKS, 1024, 0, stream>>>(cursor, rowp, part);
    scan2<<<1, 64, 0, stream>>>(part);
    scan3<<<SCAN_BLOCKS, 1024, 0, stream>>>(rowp, cursor, part);
    scatter_kernel<<<(N_EDGES + 255) / 256, 256, 0, stream>>>(esrc, edst, ew, cursor, epack);

    const int grid = (N_NODES + 63) / 64;   // 782

    // x0 = relu(x @ W_lin + b_lin) -> bf16 rows
    gemm128<true><<<grid, 256, 0, stream>>>(x, Wlin, blin, nullptr, x0B, 0.f, 1.f);

    const unsigned short* hin = x0B;
    for (int l = 0; l < 8; l++) {
        spmm5<<<grid, 256, 0, stream>>>(hin, x0B, rowp, epack, mB);
        float beta = logf(0.5f / (float)(l + 1) + 1.f);
        gemm128<false><<<grid, 256, 0, stream>>>(mB, Wcv + (size_t)l * DIM * DIM, nullptr,
                                                 (l == 7) ? out : nullptr,
                                                 (l < 7) ? hB : nullptr,
                                                 1.f - beta, beta);
        hin = hB;
    }
}